// Round 7
// baseline (842.261 us; speedup 1.0000x reference)
//
#include <hip/hip_runtime.h>
#include <math.h>
#include <stdint.h>

#define N_HEADS 4
#define N_NODES 10000
#define NPAD 10112           /* multiple of 128 */
#define NPG (NPAD / 32)      /* 316 node-groups of 32 */
#define EMB 128
#define N_BATCH 4096
#define NQ (2 * N_BATCH)     /* 8192 queries: [src(4096), dst(4096)] */
#define K 8
#define TQ 64                /* queries per block (2 row-blocks of 32) */
#define TN 128               /* nodes per iteration (4 groups of 32) */
#define NTILES (NPAD / TN)   /* 79 */
#define PH 2                 /* warm-up tiles (256 nodes) */
#define CAP 32               /* per-query candidate list capacity */
#define WIN 0.5f             /* filter window: ~21 sigma of hi-only bf16 err */

typedef __attribute__((ext_vector_type(8))) __bf16 bf16x8;
typedef __attribute__((ext_vector_type(8))) unsigned short ushortx8;
typedef __attribute__((ext_vector_type(16))) float floatx16;

// ---------------------------------------------------------------------------
// helpers
// ---------------------------------------------------------------------------
__device__ __forceinline__ unsigned short f2bf(float x) {
  unsigned u = __float_as_uint(x);
  u += 0x7fff + ((u >> 16) & 1);           // round-to-nearest-even
  return (unsigned short)(u >> 16);
}
// bf16 bits rounded toward +inf (conservative threshold)
__device__ __forceinline__ uint32_t bfup(float f) {
  uint32_t u = __float_as_uint(f);
  return (f >= 0.f) ? ((u + 0xFFFFu) >> 16) : (u >> 16);
}

// sorted ascending top-8 insertion
__device__ __forceinline__ void insert8(float* bs, int* bi, float s, int node) {
  if (s < bs[K - 1]) {
    #pragma unroll
    for (int k2 = K - 1; k2 >= 0; --k2) {
      if (!(s < bs[k2])) break;
      if (k2 < K - 1) { bs[k2 + 1] = bs[k2]; bi[k2 + 1] = bi[k2]; }
      bs[k2] = s; bi[k2] = node;
    }
  }
}

// permuted chunk offset (in ushorts) for row (32g+lm), chunk c (c = ks*2+lh)
// layout: [g][ks][lh][lm] x 8 ushorts  => g*4096 + ks*512 + lh*256 + lm*8
__device__ __forceinline__ size_t pchunk(int g, int c, int lm) {
  return (size_t)g * 4096 + (size_t)(c >> 1) * 512 + (size_t)(c & 1) * 256 + lm * 8;
}

// ---------------------------------------------------------------------------
// Kernel P: split E into bf16 HI ONLY in MFMA-B-fragment-permuted layout,
// plus exact f32 norms. Grid (NPG, N_HEADS), 256 thr.
// ---------------------------------------------------------------------------
__global__ __launch_bounds__(256) void prep_kernel(
    const float* __restrict__ E, unsigned short* __restrict__ EhiP,
    float* __restrict__ y2g) {
  __shared__ float s_p[8][33];
  const int h = blockIdx.y, g = blockIdx.x;
  const int lm = threadIdx.x & 31, c8 = threadIdx.x >> 5;
  const int n = g * 32 + lm;
  float x[16];
  #pragma unroll
  for (int j = 0; j < 16; ++j) x[j] = 0.f;
  if (n < N_NODES) {
    const float* src = E + (size_t)(h * N_NODES + n) * EMB + c8 * 16;
    #pragma unroll
    for (int j = 0; j < 4; ++j) {
      float4 v = *(const float4*)(src + j * 4);
      x[j * 4 + 0] = v.x; x[j * 4 + 1] = v.y; x[j * 4 + 2] = v.z; x[j * 4 + 3] = v.w;
    }
  }
  float part = 0.f;
  ushortx8 hi[2];
  #pragma unroll
  for (int j = 0; j < 16; ++j) {
    part += x[j] * x[j];
    hi[j >> 3][j & 7] = f2bf(x[j]);
  }
  size_t base = (size_t)h * NPG * 4096;
  #pragma unroll
  for (int lh = 0; lh < 2; ++lh)
    *(ushortx8*)&EhiP[base + pchunk(g, c8 * 2 + lh, lm)] = hi[lh];
  s_p[c8][lm] = part;
  __syncthreads();
  if (threadIdx.x < 32) {
    int nn = g * 32 + threadIdx.x;
    float s = 0.f;
    #pragma unroll
    for (int j = 0; j < 8; ++j) s += s_p[j][threadIdx.x];
    y2g[h * NPAD + nn] = (nn < N_NODES) ? s : 1e30f;
  }
}

// ---------------------------------------------------------------------------
// Kernel A: coarse-filter / exact-refine MFMA knn. 512 thr / 8 waves.
// R6 diagnosis chain: R3/R5 (2 waves/SIMD, ~124/128 VGPR) are latency-bound:
// no register headroom to keep 8 B-loads in flight -> compiler sinks loads
// to just-before-use with per-ks vmcnt waits -> each tile pays ~8 serial
// L2 latencies with only 2 waves to cover (slot 9.4K cyc, 65% stall;
// R5's VGPR=124 < its 176-reg nominal live set proves the dbuf was elided).
// Fix: wave w owns ONE (row-block w>>2, node-group w&3) pair ->
//   per-wave live ~80 VGPR (a[8]+acc+thrp) -> ~45 regs of load headroom;
//   512 blocks x 2/CU x 8 waves = 4 waves/SIMD on all 256 CUs (2x R5);
//   B-reuse x2 kept (2 waves/block per fragment, L1-served).
// LDS 37.9KB: warm-up dump two-passed through 16KB s_x (R4-verified
// pattern); CAP 41->32 with extra merges at t=48,64 (spans <=16 tiles,
// expected insertions/span ~5.5 << 32). __launch_bounds__(512,4), NOT
// amdgpu_waves_per_eu (R4's allocator pathology).
// Selection machinery logic (window filter + merges + exact f32 refine)
// unchanged from the verified path.
// ---------------------------------------------------------------------------
__global__ __launch_bounds__(512, 4) void knn_kernel(
    const unsigned short* __restrict__ EhiP, const float* __restrict__ y2g,
    const float* __restrict__ Ef, const int* __restrict__ be,
    int* __restrict__ samples) {
  __shared__ __align__(16) float s_x[32 * TN];              // 16 KiB scratch
  __shared__ float s_t8S[TQ * 9];
  __shared__ int   s_t8I[TQ * 9];
  __shared__ float s_lsS[TQ * CAP];
  __shared__ int   s_lsI[TQ * CAP];
  __shared__ float s_thr[TQ];
  __shared__ int   s_cnt[TQ];

  const int id = blockIdx.x;                     // 512 blocks
  const int h = (id & 7) >> 1;                   // head -> XCD pair
  const int qt = ((id >> 3) << 1) | (id & 1);    // 0..127
  const int tid = threadIdx.x;
  const int lane = tid & 63;
  const int w = tid >> 6;                        // wave 0..7
  const int rb = w >> 2;                         // row-block 0/1 (queries)
  const int grp = w & 3;                         // node group 0..3
  const int lm = lane & 31, lh = lane >> 5;
  const unsigned short* EhiH = EhiP + (size_t)h * NPG * 4096;
  const float* y2H = y2g + h * NPAD;
  const float* EH = Ef + (size_t)h * N_NODES * EMB;

  // ---- prologue: A-fragments for this wave's row-block (32 VGPR) ----
  bf16x8 a[8];
  {
    int q0 = be[qt * TQ + rb * 32 + lm];
    int g0 = q0 >> 5, l0 = q0 & 31;
    #pragma unroll
    for (int ks = 0; ks < 8; ++ks)
      a[ks] = *(const bf16x8*)&EhiH[pchunk(g0, ks * 2 + lh, l0)];
  }

  // warm-up scan roles: 8 threads per query, each owns a 16-col stripe
  const int qsel = tid >> 3;                     // 0..63
  const int csel = tid & 7;                      // 0..7
  const int myq = be[qt * TQ + qsel];
  float bs[K]; int bi[K];
  #pragma unroll
  for (int k2 = 0; k2 < K; ++k2) { bs[k2] = 1e30f; bi[k2] = 0x7fffffff; }
  if (tid < TQ) s_cnt[tid] = 0;

  const int bnode = 32 * grp + lm;               // node within 128-tile
  const unsigned short* bhp = EhiH + (size_t)grp * 4096 + lane * 8;

  // ---- warm-up: PH tiles, two dump/scan passes (16KB s_x) ----
  #pragma unroll 1
  for (int t = 0; t < PH; ++t) {
    const size_t goff = (size_t)t * 16384;       // 4 groups * 4096 ushorts
    float ny = y2H[t * TN + bnode];
    floatx16 acc = {0.f, 0.f, 0.f, 0.f, 0.f, 0.f, 0.f, 0.f,
                    0.f, 0.f, 0.f, 0.f, 0.f, 0.f, 0.f, 0.f};
    #pragma unroll
    for (int ks = 0; ks < 8; ++ks) {
      bf16x8 vbh = *(const bf16x8*)(bhp + goff + ks * 512);
      acc = __builtin_amdgcn_mfma_f32_32x32x16_bf16(a[ks], vbh, acc, 0, 0, 0);
    }
    // pass A: row-block 0 dumps; queries 0..31 scan
    if (rb == 0) {
      #pragma unroll
      for (int r = 0; r < 16; ++r) {
        int row = (r & 3) + 8 * (r >> 2) + 4 * lh;
        s_x[row * TN + bnode] = fmaf(-2.f, acc[r], ny);
      }
    }
    __syncthreads();
    if (qsel < 32) {
      #pragma unroll
      for (int s = 0; s < 16; ++s) {
        int j = csel * 16 + ((s + qsel) & 15);
        float sc = s_x[qsel * TN + j];
        int node = t * TN + j;
        if (node != myq) insert8(bs, bi, sc, node);
      }
    }
    __syncthreads();
    // pass B: row-block 1 dumps; queries 32..63 scan
    if (rb == 1) {
      #pragma unroll
      for (int r = 0; r < 16; ++r) {
        int row = (r & 3) + 8 * (r >> 2) + 4 * lh;
        s_x[row * TN + bnode] = fmaf(-2.f, acc[r], ny);
      }
    }
    __syncthreads();
    if (qsel >= 32) {
      #pragma unroll
      for (int s = 0; s < 16; ++s) {
        int j = csel * 16 + ((s + qsel) & 15);
        float sc = s_x[(qsel - 32) * TN + j];
        int node = t * TN + j;
        if (node != myq) insert8(bs, bi, sc, node);
      }
    }
    __syncthreads();
  }

  // ---- first merge: two phases of 256 threads through 16KB scratch ----
  {
    float* scrS = (float*)s_x;                   // 2048 floats
    int*   scrI = (int*)s_x + 2048;              // 2048 ints
    #pragma unroll 1
    for (int ph = 0; ph < 2; ++ph) {
      if ((tid >> 8) == ph) {
        int lt = tid & 255;
        #pragma unroll
        for (int k2 = 0; k2 < K; ++k2) {
          scrS[lt * 8 + k2] = bs[k2]; scrI[lt * 8 + k2] = bi[k2];
        }
      }
      __syncthreads();
      if (tid < 32) {
        int q = ph * 32 + tid;
        float ts[K]; int ti[K];
        #pragma unroll
        for (int k2 = 0; k2 < K; ++k2) { ts[k2] = 1e30f; ti[k2] = 0x7fffffff; }
        for (int kk = 0; kk < 64; ++kk) {
          int e = (kk + q) & 63;                 // bank-rotated scan
          insert8(ts, ti, scrS[tid * 64 + e], scrI[tid * 64 + e]);
        }
        float thr = ts[K - 1], win = thr + WIN;
        int nc = 0;
        for (int kk = 0; kk < 64; ++kk) {
          int e = (kk + q) & 63;
          float sv = scrS[tid * 64 + e]; int iv = scrI[tid * 64 + e];
          if (sv <= win && nc < CAP) {
            bool dup = false;
            #pragma unroll
            for (int j = 0; j < K; ++j) dup = dup || (ti[j] == iv);
            if (!dup) { s_lsS[q * CAP + nc] = sv; s_lsI[q * CAP + nc] = iv; ++nc; }
          }
        }
        s_cnt[q] = nc;
        s_thr[q] = win;                          // inflated filter threshold
        #pragma unroll
        for (int k2 = 0; k2 < K; ++k2) { s_t8S[q * 9 + k2] = ts[k2]; s_t8I[q * 9 + k2] = ti[k2]; }
      }
      __syncthreads();
    }
  }

  // packed round-up bf16 thresholds: 8 regs for this wave's row-block
  uint32_t thrp[8];
  #pragma unroll
  for (int j = 0; j < 8; ++j) {
    int r0 = 2 * j, r1 = 2 * j + 1;
    int w0 = (r0 & 3) + 8 * (r0 >> 2) + 4 * lh;
    int w1r = (r1 & 3) + 8 * (r1 >> 2) + 4 * lh;
    thrp[j] = bfup(s_thr[rb * 32 + w0]) | (bfup(s_thr[rb * 32 + w1r]) << 16);
  }

  // ---- steady state: barrier-free tiles, reg-A MFMA + window filter ----
  #pragma unroll 1
  for (int t = PH; t < NTILES; ++t) {
    if (t == 4 || t == 8 || t == 16 || t == 32 || t == 48 || t == 64) {
      __syncthreads();
      if (tid < TQ) {
        int q = tid;
        int myqm = be[qt * TQ + q];
        float ts[K]; int ti[K];
        #pragma unroll
        for (int k2 = 0; k2 < K; ++k2) { ts[k2] = s_t8S[q * 9 + k2]; ti[k2] = s_t8I[q * 9 + k2]; }
        int cnt = s_cnt[q]; if (cnt > CAP) cnt = CAP;
        for (int p = 0; p < cnt; ++p) {
          int iv = s_lsI[q * CAP + p];
          if (iv != myqm) insert8(ts, ti, s_lsS[q * CAP + p], iv);
        }
        float thr = ts[K - 1], win = thr + WIN;
        // compact list in-place: window survivors not in new t8, not self
        int nc = 0;
        for (int p = 0; p < cnt; ++p) {
          float sv = s_lsS[q * CAP + p]; int iv = s_lsI[q * CAP + p];
          if (sv <= win && iv != myqm) {
            bool dup = false;
            #pragma unroll
            for (int j = 0; j < K; ++j) dup = dup || (ti[j] == iv);
            if (!dup && nc < CAP) { s_lsS[q * CAP + nc] = sv; s_lsI[q * CAP + nc] = iv; ++nc; }
          }
        }
        // displaced old-t8 entries within the window must be kept too
        #pragma unroll
        for (int k2 = 0; k2 < K; ++k2) {
          float sv = s_t8S[q * 9 + k2]; int iv = s_t8I[q * 9 + k2];
          if (sv <= win && iv != myqm && nc < CAP) {
            bool dup = false;
            #pragma unroll
            for (int j = 0; j < K; ++j) dup = dup || (ti[j] == iv);
            if (!dup) { s_lsS[q * CAP + nc] = sv; s_lsI[q * CAP + nc] = iv; ++nc; }
          }
        }
        s_cnt[q] = nc;
        s_thr[q] = win;
        #pragma unroll
        for (int k2 = 0; k2 < K; ++k2) { s_t8S[q * 9 + k2] = ts[k2]; s_t8I[q * 9 + k2] = ti[k2]; }
      }
      __syncthreads();
      #pragma unroll
      for (int j = 0; j < 8; ++j) {
        int r0 = 2 * j, r1 = 2 * j + 1;
        int w0 = (r0 & 3) + 8 * (r0 >> 2) + 4 * lh;
        int w1r = (r1 & 3) + 8 * (r1 >> 2) + 4 * lh;
        thrp[j] = bfup(s_thr[rb * 32 + w0]) | (bfup(s_thr[rb * 32 + w1r]) << 16);
      }
    }

    const size_t goff = (size_t)t * 16384;
    float ny = y2H[t * TN + bnode];
    floatx16 acc = {0.f, 0.f, 0.f, 0.f, 0.f, 0.f, 0.f, 0.f,
                    0.f, 0.f, 0.f, 0.f, 0.f, 0.f, 0.f, 0.f};
    #pragma unroll
    for (int ks = 0; ks < 8; ++ks) {
      bf16x8 vbh = *(const bf16x8*)(bhp + goff + ks * 512);
      acc = __builtin_amdgcn_mfma_f32_32x32x16_bf16(a[ks], vbh, acc, 0, 0, 0);
    }
    const int node = t * TN + bnode;
    #pragma unroll
    for (int r = 0; r < 16; ++r) {
      float sc = fmaf(-2.f, acc[r], ny);
      float th = (r & 1) ? __uint_as_float(thrp[r >> 1] & 0xFFFF0000u)
                         : __uint_as_float(thrp[r >> 1] << 16);
      if (sc < th) {                             // rare (self / window / top-8)
        int q = rb * 32 + (r & 3) + 8 * (r >> 2) + 4 * lh;
        int p = atomicAdd(&s_cnt[q], 1);
        if (p < CAP) { s_lsS[q * CAP + p] = sc; s_lsI[q * CAP + p] = node; }
      }
    }
  }

  // ---- final: exact f32 refine of all candidates, then select ----
  __syncthreads();
  {
    int q = tid >> 3, k = tid & 7;               // 8 threads per query
    int qn = be[qt * TQ + q];
    const float4* Eq = (const float4*)(EH + (size_t)qn * EMB);
    // phase A: refine t8 entry k of query q
    int iv = s_t8I[q * 9 + k];
    if (iv < N_NODES) {
      const float4* En = (const float4*)(EH + (size_t)iv * EMB);
      float d0 = 0.f, d1 = 0.f, d2 = 0.f, d3 = 0.f;
      #pragma unroll
      for (int d = 0; d < 32; ++d) {
        float4 a2 = Eq[d], b = En[d];
        d0 += a2.x * b.x; d1 += a2.y * b.y; d2 += a2.z * b.z; d3 += a2.w * b.w;
      }
      s_t8S[q * 9 + k] = y2H[iv] - 2.f * ((d0 + d1) + (d2 + d3));
    }
    // phase B: refine list entries (strided over the 8 threads of query q)
    int cnt = s_cnt[q]; if (cnt > CAP) cnt = CAP;
    for (int p = k; p < cnt; p += 8) {
      int jv = s_lsI[q * CAP + p];
      if (jv < N_NODES && jv != qn) {
        const float4* En = (const float4*)(EH + (size_t)jv * EMB);
        float d0 = 0.f, d1 = 0.f, d2 = 0.f, d3 = 0.f;
        #pragma unroll
        for (int d = 0; d < 32; ++d) {
          float4 a2 = Eq[d], b = En[d];
          d0 += a2.x * b.x; d1 += a2.y * b.y; d2 += a2.z * b.z; d3 += a2.w * b.w;
        }
        s_lsS[q * CAP + p] = y2H[jv] - 2.f * ((d0 + d1) + (d2 + d3));
      }
    }
  }
  __syncthreads();
  if (tid < TQ) {
    int q = tid;
    int myqm = be[qt * TQ + q];
    float ts[K]; int ti[K];
    #pragma unroll
    for (int k2 = 0; k2 < K; ++k2) { ts[k2] = 1e30f; ti[k2] = 0x7fffffff; }
    #pragma unroll
    for (int k2 = 0; k2 < K; ++k2)
      insert8(ts, ti, s_t8S[q * 9 + k2], s_t8I[q * 9 + k2]);
    int cnt = s_cnt[q]; if (cnt > CAP) cnt = CAP;
    for (int p = 0; p < cnt; ++p) {
      int iv = s_lsI[q * CAP + p];
      if (iv != myqm) insert8(ts, ti, s_lsS[q * CAP + p], iv);
    }
    size_t base = ((size_t)h * NQ + qt * TQ + q) * K;
    #pragma unroll
    for (int k2 = 0; k2 < K; ++k2) samples[base + k2] = ti[k2];
  }
}

// ---------------------------------------------------------------------------
// Kernel B: epilogue (unchanged — verified absmax 0.0).
// ---------------------------------------------------------------------------
__global__ __launch_bounds__(256) void predict_kernel(
    const float* __restrict__ E, const float* __restrict__ F,
    const float* __restrict__ unc, const float* __restrict__ adj,
    const int* __restrict__ be, const int* __restrict__ samples,
    float* __restrict__ out) {
  int b = blockIdx.x;
  int h = threadIdx.x >> 6;
  int lane = threadIdx.x & 63;
  __shared__ float smv[N_HEADS];

  int srcb = be[b];
  int dstb = be[N_BATCH + b];
  const float* Eh = E + (size_t)h * N_NODES * EMB;
  const float* Fh = F + (size_t)h * N_NODES * EMB;
  float2 es = *(const float2*)(Eh + (size_t)srcb * EMB + 2 * lane);
  float2 ed = *(const float2*)(Eh + (size_t)dstb * EMB + 2 * lane);
  float2 fs = *(const float2*)(Fh + (size_t)srcb * EMB + 2 * lane);
  float2 fd = *(const float2*)(Fh + (size_t)dstb * EMB + 2 * lane);
  float u = unc[0];

  float logit[16], dist[16];
  #pragma unroll
  for (int j = 0; j < 16; ++j) {
    bool isrc = (j < 8);
    int qrow = isrc ? b : (N_BATCH + b);
    int s = samples[((size_t)h * NQ + qrow) * K + (j & 7)];
    float2 ev = *(const float2*)(Eh + (size_t)s * EMB + 2 * lane);
    float2 bb = isrc ? es : ed;
    float2 g = isrc ? fd : fs;
    float dx = bb.x - ev.x, dy = bb.y - ev.y;
    float dot = dx * g.x + dy * g.y;
    float nrm = dx * dx + dy * dy;
    #pragma unroll
    for (int o = 32; o > 0; o >>= 1) {
      dot += __shfl_xor(dot, o);
      nrm += __shfl_xor(nrm, o);
    }
    float a = isrc ? adj[(size_t)s * N_NODES + dstb]
                   : adj[(size_t)srcb * N_NODES + s];
    logit[j] = dot + u * (2.0f * a - 1.0f);
    dist[j] = sqrtf(nrm);
  }

  float m = 0.0f;  // sentinel: 1 - 1.0 = 0
  #pragma unroll
  for (int j = 0; j < 16; ++j) m = fmaxf(m, 1.0f - dist[j]);
  float Z = 8.0f * expf(-m);
  float num = 0.0f;
  #pragma unroll
  for (int j = 0; j < 16; ++j) {
    float e = expf(1.0f - dist[j] - m);
    Z += e;
    num += logit[j] * e;
  }
  if (lane == 0) smv[h] = num / Z;
  __syncthreads();
  if (threadIdx.x == 0) {
    float t = 0.25f * (smv[0] + smv[1] + smv[2] + smv[3]);
    out[b] = 1.0f / (1.0f + expf(-t));
  }
}

// ---------------------------------------------------------------------------
extern "C" void kernel_launch(void* const* d_in, const int* in_sizes, int n_in,
                              void* d_out, int out_size, void* d_ws,
                              size_t ws_size, hipStream_t stream) {
  const float* E = (const float*)d_in[0];
  const float* F = (const float*)d_in[1];
  const float* U = (const float*)d_in[2];
  const float* A = (const float*)d_in[3];
  const int* be = (const int*)d_in[4];
  float* out = (float*)d_out;

  // ws layout (256B-aligned): EhiP 10,354,688 | y2g 162,048 |
  //   samples 1,048,576   (~11.6 MB)
  char* w = (char*)d_ws;
  unsigned short* EhiP = (unsigned short*)(w);
  float* y2g = (float*)(w + 10354688);
  int* samples = (int*)(w + 10516736);

  prep_kernel<<<dim3(NPG, N_HEADS), 256, 0, stream>>>(E, EhiP, y2g);
  knn_kernel<<<dim3((NQ / TQ) * N_HEADS), 512, 0, stream>>>(EhiP, y2g, E, be, samples);
  predict_kernel<<<dim3(N_BATCH), 256, 0, stream>>>(E, F, U, A, be, samples, out);
}

// Round 8
// 775.925 us; speedup vs baseline: 1.0855x; 1.0855x over previous
//
#include <hip/hip_runtime.h>
#include <math.h>
#include <stdint.h>

#define N_HEADS 4
#define N_NODES 10000
#define NPAD 10112           /* multiple of 128 */
#define NPG (NPAD / 32)      /* 316 node-groups of 32 */
#define EMB 128
#define N_BATCH 4096
#define NQ (2 * N_BATCH)     /* 8192 queries: [src(4096), dst(4096)] */
#define K 8
#define TQ 64                /* queries per block (2 row-blocks of 32) */
#define TN 128               /* nodes per iteration (4 groups of 32) */
#define NTILES (NPAD / TN)   /* 79 */
#define PH 2                 /* warm-up tiles (256 nodes) */
#define CAP 41               /* per-query candidate list capacity (odd) */
#define WIN 0.5f             /* filter window: ~21 sigma of hi-only bf16 err */

typedef __attribute__((ext_vector_type(8))) __bf16 bf16x8;
typedef __attribute__((ext_vector_type(8))) unsigned short ushortx8;
typedef __attribute__((ext_vector_type(16))) float floatx16;

// ---------------------------------------------------------------------------
// helpers
// ---------------------------------------------------------------------------
__device__ __forceinline__ unsigned short f2bf(float x) {
  unsigned u = __float_as_uint(x);
  u += 0x7fff + ((u >> 16) & 1);           // round-to-nearest-even
  return (unsigned short)(u >> 16);
}
// bf16 bits rounded toward +inf (conservative threshold)
__device__ __forceinline__ uint32_t bfup(float f) {
  uint32_t u = __float_as_uint(f);
  return (f >= 0.f) ? ((u + 0xFFFFu) >> 16) : (u >> 16);
}

// sorted ascending top-8 insertion
__device__ __forceinline__ void insert8(float* bs, int* bi, float s, int node) {
  if (s < bs[K - 1]) {
    #pragma unroll
    for (int k2 = K - 1; k2 >= 0; --k2) {
      if (!(s < bs[k2])) break;
      if (k2 < K - 1) { bs[k2 + 1] = bs[k2]; bi[k2 + 1] = bi[k2]; }
      bs[k2] = s; bi[k2] = node;
    }
  }
}

// permuted chunk offset (in ushorts) for row (32g+lm), chunk c (c = ks*2+lh)
// layout: [g][ks][lh][lm] x 8 ushorts  => g*4096 + ks*512 + lh*256 + lm*8
__device__ __forceinline__ size_t pchunk(int g, int c, int lm) {
  return (size_t)g * 4096 + (size_t)(c >> 1) * 512 + (size_t)(c & 1) * 256 + lm * 8;
}

// ---------------------------------------------------------------------------
// Kernel P: split E into bf16 HI ONLY in MFMA-B-fragment-permuted layout,
// plus exact f32 norms. Grid (NPG, N_HEADS), 256 thr.
// ---------------------------------------------------------------------------
__global__ __launch_bounds__(256) void prep_kernel(
    const float* __restrict__ E, unsigned short* __restrict__ EhiP,
    float* __restrict__ y2g) {
  __shared__ float s_p[8][33];
  const int h = blockIdx.y, g = blockIdx.x;
  const int lm = threadIdx.x & 31, c8 = threadIdx.x >> 5;
  const int n = g * 32 + lm;
  float x[16];
  #pragma unroll
  for (int j = 0; j < 16; ++j) x[j] = 0.f;
  if (n < N_NODES) {
    const float* src = E + (size_t)(h * N_NODES + n) * EMB + c8 * 16;
    #pragma unroll
    for (int j = 0; j < 4; ++j) {
      float4 v = *(const float4*)(src + j * 4);
      x[j * 4 + 0] = v.x; x[j * 4 + 1] = v.y; x[j * 4 + 2] = v.z; x[j * 4 + 3] = v.w;
    }
  }
  float part = 0.f;
  ushortx8 hi[2];
  #pragma unroll
  for (int j = 0; j < 16; ++j) {
    part += x[j] * x[j];
    hi[j >> 3][j & 7] = f2bf(x[j]);
  }
  size_t base = (size_t)h * NPG * 4096;
  #pragma unroll
  for (int lh = 0; lh < 2; ++lh)
    *(ushortx8*)&EhiP[base + pchunk(g, c8 * 2 + lh, lm)] = hi[lh];
  s_p[c8][lm] = part;
  __syncthreads();
  if (threadIdx.x < 32) {
    int nn = g * 32 + threadIdx.x;
    float s = 0.f;
    #pragma unroll
    for (int j = 0; j < 8; ++j) s += s_p[j][threadIdx.x];
    y2g[h * NPAD + nn] = (nn < N_NODES) ? s : 1e30f;
  }
}

// ---------------------------------------------------------------------------
// Kernel A: coarse-filter / exact-refine MFMA knn. TQ=64, TN=128, 256 thr,
// waves_per_eu(2,2) — EXACTLY the R5 geometry (best verified: 310us, VGPR
// 124, no spill), with ONE change: the B double-buffer prefetch is pinned
// with __builtin_amdgcn_sched_barrier(0) so the scheduler cannot sink the
// t+1 loads back to just-before-use (R5's VGPR=124 < 176-reg nominal live
// set proved the dbuf was silently elided -> each tile paid ~8 serial L2
// latencies with only 2 waves/SIMD to cover = the 68% stall).
// Steady-state loop is guard-free (t=2..76 computes t,t+1 with
// unconditional prefetch of t+1,t+2; tail computes t=78) so no control
// flow gives the scheduler an excuse to be conservative.
// NOTE (ledger): 512-thr blocks are an allocator trap (R4/R6: VGPR pinned
// 64 + spill). 256-thr + waves_per_eu(2,2) is the only config that honors
// >64 VGPR.  MFMA 32x32x16 costs ~32 cyc/SIMD (m119-derived), so R5's
// MfmaUtil=11% == 2w x 16mfma x 32cyc / 9418-cyc slot: latency-bound.
// Selection machinery (window filter + merges + exact f32 refine) unchanged
// from the verified R3/R5 path.
// ---------------------------------------------------------------------------
__global__ __launch_bounds__(256)
__attribute__((amdgpu_waves_per_eu(2, 2)))
void knn_kernel(
    const unsigned short* __restrict__ EhiP, const float* __restrict__ y2g,
    const float* __restrict__ Ef, const int* __restrict__ be,
    int* __restrict__ samples) {
  __shared__ __align__(16) float s_x[TQ * TN];              // 32 KiB scratch
  __shared__ float s_t8S[TQ * 9];
  __shared__ int   s_t8I[TQ * 9];
  __shared__ float s_lsS[TQ * CAP];
  __shared__ int   s_lsI[TQ * CAP];
  __shared__ float s_thr[TQ];
  __shared__ int   s_cnt[TQ];

  const int id = blockIdx.x;                     // 512 blocks
  const int h = (id & 7) >> 1;                   // head -> XCD pair
  const int qt = ((id >> 3) << 1) | (id & 1);    // 0..127
  const int tid = threadIdx.x;
  const int lane = tid & 63;
  const int w1 = tid >> 6;                       // node-group role 0..3
  const int lm = lane & 31, lh = lane >> 5;
  const unsigned short* EhiH = EhiP + (size_t)h * NPG * 4096;
  const float* y2H = y2g + h * NPAD;
  const float* EH = Ef + (size_t)h * N_NODES * EMB;

  // ---- prologue: gather BOTH A-fragment sets directly into registers ----
  bf16x8 a0[8], a1[8];
  {
    int q0 = be[qt * TQ + lm];
    int q1 = be[qt * TQ + 32 + lm];
    int g0 = q0 >> 5, l0 = q0 & 31;
    int g1 = q1 >> 5, l1 = q1 & 31;
    #pragma unroll
    for (int ks = 0; ks < 8; ++ks) {
      a0[ks] = *(const bf16x8*)&EhiH[pchunk(g0, ks * 2 + lh, l0)];
      a1[ks] = *(const bf16x8*)&EhiH[pchunk(g1, ks * 2 + lh, l1)];
    }
  }

  // warm-up scan roles: 4 threads per query, each owns a 32-col stripe
  const int qsel = tid >> 2;                     // 0..63
  const int csel = tid & 3;                      // 0..3
  const int myq = be[qt * TQ + qsel];
  float bs[K]; int bi[K];
  #pragma unroll
  for (int k2 = 0; k2 < K; ++k2) { bs[k2] = 1e30f; bi[k2] = 0x7fffffff; }
  if (tid < TQ) s_cnt[tid] = 0;

  const int bnode = 32 * w1 + lm;                // node within 128-tile
  const unsigned short* bhp = EhiH + (size_t)w1 * 4096 + lane * 8;

  // ---- warm-up: PH tiles via score dump + private insert ----
  #pragma unroll 1
  for (int t = 0; t < PH; ++t) {
    const size_t goff = (size_t)t * 16384;       // 4 groups * 4096 ushorts
    float ny = y2H[t * TN + bnode];
    floatx16 acc0 = {0.f, 0.f, 0.f, 0.f, 0.f, 0.f, 0.f, 0.f,
                     0.f, 0.f, 0.f, 0.f, 0.f, 0.f, 0.f, 0.f};
    floatx16 acc1 = acc0;
    #pragma unroll
    for (int ks = 0; ks < 8; ++ks) {
      bf16x8 vbh = *(const bf16x8*)(bhp + goff + ks * 512);
      acc0 = __builtin_amdgcn_mfma_f32_32x32x16_bf16(a0[ks], vbh, acc0, 0, 0, 0);
      acc1 = __builtin_amdgcn_mfma_f32_32x32x16_bf16(a1[ks], vbh, acc1, 0, 0, 0);
    }
    #pragma unroll
    for (int r = 0; r < 16; ++r) {
      int row = (r & 3) + 8 * (r >> 2) + 4 * lh;
      s_x[row * TN + bnode] = fmaf(-2.f, acc0[r], ny);
      s_x[(row + 32) * TN + bnode] = fmaf(-2.f, acc1[r], ny);
    }
    __syncthreads();
    int nbp = t * TN;
    #pragma unroll
    for (int s = 0; s < 32; ++s) {
      int j = csel * 32 + ((s + qsel) & 31);
      float sc = s_x[qsel * TN + j];
      int node = nbp + j;
      if (node != myq) insert8(bs, bi, sc, node);
    }
    __syncthreads();
  }

  // ---- first merge: privates -> hi-top-8 + window compaction -> list ----
  {
    float* scrS = (float*)s_x;                   // 2048 floats
    int*   scrI = (int*)s_x + TQ * 32;           // 2048 ints
    #pragma unroll
    for (int k2 = 0; k2 < K; ++k2) {
      scrS[tid * 8 + k2] = bs[k2]; scrI[tid * 8 + k2] = bi[k2];
    }
    __syncthreads();
    if (tid < TQ) {
      int q = tid;
      float ts[K]; int ti[K];
      #pragma unroll
      for (int k2 = 0; k2 < K; ++k2) { ts[k2] = 1e30f; ti[k2] = 0x7fffffff; }
      for (int kk = 0; kk < 32; ++kk) {
        int e = (kk + q) & 31;                   // bank-rotated scan
        insert8(ts, ti, scrS[q * 32 + e], scrI[q * 32 + e]);
      }
      float thr = ts[K - 1], win = thr + WIN;
      // window compaction: warm-up entries within win, not already in t8
      int nc = 0;
      for (int kk = 0; kk < 32; ++kk) {
        int e = (kk + q) & 31;
        float sv = scrS[q * 32 + e]; int iv = scrI[q * 32 + e];
        if (sv <= win && nc < CAP) {
          bool dup = false;
          #pragma unroll
          for (int j = 0; j < K; ++j) dup = dup || (ti[j] == iv);
          if (!dup) { s_lsS[q * CAP + nc] = sv; s_lsI[q * CAP + nc] = iv; ++nc; }
        }
      }
      s_cnt[q] = nc;
      s_thr[q] = win;                            // inflated filter threshold
      #pragma unroll
      for (int k2 = 0; k2 < K; ++k2) { s_t8S[q * 9 + k2] = ts[k2]; s_t8I[q * 9 + k2] = ti[k2]; }
    }
    __syncthreads();
  }

  // packed round-up bf16 thresholds: 8 regs per row-block
  uint32_t thrp0[8], thrp1[8];
  #pragma unroll
  for (int j = 0; j < 8; ++j) {
    int r0 = 2 * j, r1 = 2 * j + 1;
    int w0 = (r0 & 3) + 8 * (r0 >> 2) + 4 * lh;
    int w1r = (r1 & 3) + 8 * (r1 >> 2) + 4 * lh;
    thrp0[j] = bfup(s_thr[w0]) | (bfup(s_thr[w1r]) << 16);
    thrp1[j] = bfup(s_thr[w0 + 32]) | (bfup(s_thr[w1r + 32]) << 16);
  }

// ---- steady state: pinned double-buffer (sched_barrier holds prefetch) ----
#define PREFETCH_T(VB, NY, TT)                                               \
  do {                                                                       \
    const size_t goff_ = (size_t)(TT) * 16384;                               \
    NY = y2H[(TT) * TN + bnode];                                             \
    _Pragma("unroll")                                                        \
    for (int ks = 0; ks < 8; ++ks)                                           \
      VB[ks] = *(const bf16x8*)(bhp + goff_ + ks * 512);                     \
  } while (0)

#define COMPUTE_T(VB, NY, TT)                                                \
  do {                                                                       \
    floatx16 acc0 = {0.f, 0.f, 0.f, 0.f, 0.f, 0.f, 0.f, 0.f,                 \
                     0.f, 0.f, 0.f, 0.f, 0.f, 0.f, 0.f, 0.f};                \
    floatx16 acc1 = acc0;                                                    \
    _Pragma("unroll")                                                        \
    for (int ks = 0; ks < 8; ++ks) {                                         \
      acc0 = __builtin_amdgcn_mfma_f32_32x32x16_bf16(a0[ks], VB[ks], acc0, 0, 0, 0); \
      acc1 = __builtin_amdgcn_mfma_f32_32x32x16_bf16(a1[ks], VB[ks], acc1, 0, 0, 0); \
    }                                                                        \
    const int node_ = (TT) * TN + bnode;                                     \
    _Pragma("unroll")                                                        \
    for (int r = 0; r < 16; ++r) {                                           \
      float sc = fmaf(-2.f, acc0[r], NY);                                    \
      float th = (r & 1) ? __uint_as_float(thrp0[r >> 1] & 0xFFFF0000u)      \
                         : __uint_as_float(thrp0[r >> 1] << 16);             \
      if (sc < th) {                                                         \
        int q_ = (r & 3) + 8 * (r >> 2) + 4 * lh;                            \
        int p_ = atomicAdd(&s_cnt[q_], 1);                                   \
        if (p_ < CAP) { s_lsS[q_ * CAP + p_] = sc; s_lsI[q_ * CAP + p_] = node_; } \
      }                                                                      \
    }                                                                        \
    _Pragma("unroll")                                                        \
    for (int r = 0; r < 16; ++r) {                                           \
      float sc = fmaf(-2.f, acc1[r], NY);                                    \
      float th = (r & 1) ? __uint_as_float(thrp1[r >> 1] & 0xFFFF0000u)      \
                         : __uint_as_float(thrp1[r >> 1] << 16);             \
      if (sc < th) {                                                         \
        int q_ = 32 + (r & 3) + 8 * (r >> 2) + 4 * lh;                       \
        int p_ = atomicAdd(&s_cnt[q_], 1);                                   \
        if (p_ < CAP) { s_lsS[q_ * CAP + p_] = sc; s_lsI[q_ * CAP + p_] = node_; } \
      }                                                                      \
    }                                                                        \
  } while (0)

  bf16x8 vbA[8], vbB[8];
  float nyA = 0.f, nyB = 0.f;
  PREFETCH_T(vbA, nyA, PH);

  // main loop: t = 2..76 (computes t and t+1); tail computes t = 78.
  #pragma unroll 1
  for (int t = PH; t + 2 < NTILES; t += 2) {
    if (t == 4 || t == 8 || t == 16 || t == 32) {   // merge point (all even)
      __syncthreads();
      if (tid < TQ) {
        int q = tid;
        int myqm = be[qt * TQ + q];
        float ts[K]; int ti[K];
        #pragma unroll
        for (int k2 = 0; k2 < K; ++k2) { ts[k2] = s_t8S[q * 9 + k2]; ti[k2] = s_t8I[q * 9 + k2]; }
        int cnt = s_cnt[q]; if (cnt > CAP) cnt = CAP;
        for (int p = 0; p < cnt; ++p) {
          int iv = s_lsI[q * CAP + p];
          if (iv != myqm) insert8(ts, ti, s_lsS[q * CAP + p], iv);
        }
        float thr = ts[K - 1], win = thr + WIN;
        // compact list in-place: window survivors not in new t8, not self
        int nc = 0;
        for (int p = 0; p < cnt; ++p) {
          float sv = s_lsS[q * CAP + p]; int iv = s_lsI[q * CAP + p];
          if (sv <= win && iv != myqm) {
            bool dup = false;
            #pragma unroll
            for (int j = 0; j < K; ++j) dup = dup || (ti[j] == iv);
            if (!dup && nc < CAP) { s_lsS[q * CAP + nc] = sv; s_lsI[q * CAP + nc] = iv; ++nc; }
          }
        }
        // displaced old-t8 entries within the window must be kept too
        #pragma unroll
        for (int k2 = 0; k2 < K; ++k2) {
          float sv = s_t8S[q * 9 + k2]; int iv = s_t8I[q * 9 + k2];
          if (sv <= win && iv != myqm && nc < CAP) {
            bool dup = false;
            #pragma unroll
            for (int j = 0; j < K; ++j) dup = dup || (ti[j] == iv);
            if (!dup) { s_lsS[q * CAP + nc] = sv; s_lsI[q * CAP + nc] = iv; ++nc; }
          }
        }
        s_cnt[q] = nc;
        s_thr[q] = win;
        #pragma unroll
        for (int k2 = 0; k2 < K; ++k2) { s_t8S[q * 9 + k2] = ts[k2]; s_t8I[q * 9 + k2] = ti[k2]; }
      }
      __syncthreads();
      #pragma unroll
      for (int j = 0; j < 8; ++j) {
        int r0 = 2 * j, r1 = 2 * j + 1;
        int w0 = (r0 & 3) + 8 * (r0 >> 2) + 4 * lh;
        int w1r = (r1 & 3) + 8 * (r1 >> 2) + 4 * lh;
        thrp0[j] = bfup(s_thr[w0]) | (bfup(s_thr[w1r]) << 16);
        thrp1[j] = bfup(s_thr[w0 + 32]) | (bfup(s_thr[w1r + 32]) << 16);
      }
    }

    // prefetch t+1 (pinned), compute t; prefetch t+2 (pinned), compute t+1
    PREFETCH_T(vbB, nyB, t + 1);
    __builtin_amdgcn_sched_barrier(0);
    COMPUTE_T(vbA, nyA, t);
    PREFETCH_T(vbA, nyA, t + 2);
    __builtin_amdgcn_sched_barrier(0);
    COMPUTE_T(vbB, nyB, t + 1);
  }
  // tail: tile 78 (already in vbA)
  COMPUTE_T(vbA, nyA, NTILES - 1);
#undef PREFETCH_T
#undef COMPUTE_T

  // ---- final: exact f32 refine of all candidates, then select ----
  __syncthreads();
  {
    int q = tid >> 2, k4 = tid & 3;              // 4 threads per query
    int qn = be[qt * TQ + q];
    const float4* Eq = (const float4*)(EH + (size_t)qn * EMB);
    // phase A: refine t8 entries k4 and k4+4 of query q
    #pragma unroll
    for (int kk = 0; kk < 2; ++kk) {
      int k = k4 + kk * 4;
      int iv = s_t8I[q * 9 + k];
      if (iv < N_NODES) {
        const float4* En = (const float4*)(EH + (size_t)iv * EMB);
        float d0 = 0.f, d1 = 0.f, d2 = 0.f, d3 = 0.f;
        #pragma unroll
        for (int d = 0; d < 32; ++d) {
          float4 a = Eq[d], b = En[d];
          d0 += a.x * b.x; d1 += a.y * b.y; d2 += a.z * b.z; d3 += a.w * b.w;
        }
        s_t8S[q * 9 + k] = y2H[iv] - 2.f * ((d0 + d1) + (d2 + d3));
      }
    }
    // phase B: refine list entries (strided over the 4 threads of query q)
    int cnt = s_cnt[q]; if (cnt > CAP) cnt = CAP;
    for (int p = k4; p < cnt; p += 4) {
      int jv = s_lsI[q * CAP + p];
      if (jv < N_NODES && jv != qn) {
        const float4* En = (const float4*)(EH + (size_t)jv * EMB);
        float d0 = 0.f, d1 = 0.f, d2 = 0.f, d3 = 0.f;
        #pragma unroll
        for (int d = 0; d < 32; ++d) {
          float4 a = Eq[d], b = En[d];
          d0 += a.x * b.x; d1 += a.y * b.y; d2 += a.z * b.z; d3 += a.w * b.w;
        }
        s_lsS[q * CAP + p] = y2H[jv] - 2.f * ((d0 + d1) + (d2 + d3));
      }
    }
  }
  __syncthreads();
  if (tid < TQ) {
    int q = tid;
    int myqm = be[qt * TQ + q];
    float ts[K]; int ti[K];
    #pragma unroll
    for (int k2 = 0; k2 < K; ++k2) { ts[k2] = 1e30f; ti[k2] = 0x7fffffff; }
    #pragma unroll
    for (int k2 = 0; k2 < K; ++k2)
      insert8(ts, ti, s_t8S[q * 9 + k2], s_t8I[q * 9 + k2]);
    int cnt = s_cnt[q]; if (cnt > CAP) cnt = CAP;
    for (int p = 0; p < cnt; ++p) {
      int iv = s_lsI[q * CAP + p];
      if (iv != myqm) insert8(ts, ti, s_lsS[q * CAP + p], iv);
    }
    size_t base = ((size_t)h * NQ + qt * TQ + q) * K;
    #pragma unroll
    for (int k2 = 0; k2 < K; ++k2) samples[base + k2] = ti[k2];
  }
}

// ---------------------------------------------------------------------------
// Kernel B: epilogue (unchanged — verified absmax 0.0).
// ---------------------------------------------------------------------------
__global__ __launch_bounds__(256) void predict_kernel(
    const float* __restrict__ E, const float* __restrict__ F,
    const float* __restrict__ unc, const float* __restrict__ adj,
    const int* __restrict__ be, const int* __restrict__ samples,
    float* __restrict__ out) {
  int b = blockIdx.x;
  int h = threadIdx.x >> 6;
  int lane = threadIdx.x & 63;
  __shared__ float smv[N_HEADS];

  int srcb = be[b];
  int dstb = be[N_BATCH + b];
  const float* Eh = E + (size_t)h * N_NODES * EMB;
  const float* Fh = F + (size_t)h * N_NODES * EMB;
  float2 es = *(const float2*)(Eh + (size_t)srcb * EMB + 2 * lane);
  float2 ed = *(const float2*)(Eh + (size_t)dstb * EMB + 2 * lane);
  float2 fs = *(const float2*)(Fh + (size_t)srcb * EMB + 2 * lane);
  float2 fd = *(const float2*)(Fh + (size_t)dstb * EMB + 2 * lane);
  float u = unc[0];

  float logit[16], dist[16];
  #pragma unroll
  for (int j = 0; j < 16; ++j) {
    bool isrc = (j < 8);
    int qrow = isrc ? b : (N_BATCH + b);
    int s = samples[((size_t)h * NQ + qrow) * K + (j & 7)];
    float2 ev = *(const float2*)(Eh + (size_t)s * EMB + 2 * lane);
    float2 bb = isrc ? es : ed;
    float2 g = isrc ? fd : fs;
    float dx = bb.x - ev.x, dy = bb.y - ev.y;
    float dot = dx * g.x + dy * g.y;
    float nrm = dx * dx + dy * dy;
    #pragma unroll
    for (int o = 32; o > 0; o >>= 1) {
      dot += __shfl_xor(dot, o);
      nrm += __shfl_xor(nrm, o);
    }
    float a = isrc ? adj[(size_t)s * N_NODES + dstb]
                   : adj[(size_t)srcb * N_NODES + s];
    logit[j] = dot + u * (2.0f * a - 1.0f);
    dist[j] = sqrtf(nrm);
  }

  float m = 0.0f;  // sentinel: 1 - 1.0 = 0
  #pragma unroll
  for (int j = 0; j < 16; ++j) m = fmaxf(m, 1.0f - dist[j]);
  float Z = 8.0f * expf(-m);
  float num = 0.0f;
  #pragma unroll
  for (int j = 0; j < 16; ++j) {
    float e = expf(1.0f - dist[j] - m);
    Z += e;
    num += logit[j] * e;
  }
  if (lane == 0) smv[h] = num / Z;
  __syncthreads();
  if (threadIdx.x == 0) {
    float t = 0.25f * (smv[0] + smv[1] + smv[2] + smv[3]);
    out[b] = 1.0f / (1.0f + expf(-t));
  }
}

// ---------------------------------------------------------------------------
extern "C" void kernel_launch(void* const* d_in, const int* in_sizes, int n_in,
                              void* d_out, int out_size, void* d_ws,
                              size_t ws_size, hipStream_t stream) {
  const float* E = (const float*)d_in[0];
  const float* F = (const float*)d_in[1];
  const float* U = (const float*)d_in[2];
  const float* A = (const float*)d_in[3];
  const int* be = (const int*)d_in[4];
  float* out = (float*)d_out;

  // ws layout (256B-aligned): EhiP 10,354,688 | y2g 162,048 |
  //   samples 1,048,576   (~11.6 MB)
  char* w = (char*)d_ws;
  unsigned short* EhiP = (unsigned short*)(w);
  float* y2g = (float*)(w + 10354688);
  int* samples = (int*)(w + 10516736);

  prep_kernel<<<dim3(NPG, N_HEADS), 256, 0, stream>>>(E, EhiP, y2g);
  knn_kernel<<<dim3((NQ / TQ) * N_HEADS), 256, 0, stream>>>(EhiP, y2g, E, be, samples);
  predict_kernel<<<dim3(N_BATCH), 256, 0, stream>>>(E, F, U, A, be, samples, out);
}